// Round 1
// baseline (292.665 us; speedup 1.0000x reference)
//
#include <hip/hip_runtime.h>

typedef __attribute__((ext_vector_type(8))) __bf16 bf16x8;
typedef __attribute__((ext_vector_type(4))) float f32x4;
typedef __attribute__((ext_vector_type(4))) unsigned short ushort4v;

__device__ __forceinline__ unsigned short f2bf(float x) {
  union { float f; unsigned u; } v; v.f = x;
  unsigned r = v.u + 0x7fffu + ((v.u >> 16) & 1u);
  return (unsigned short)(r >> 16);
}

#define GLDS16(g, l) __builtin_amdgcn_global_load_lds( \
    (__attribute__((address_space(1))) void*)(g), \
    (__attribute__((address_space(3))) void*)(l), 16, 0, 0)

__global__ void cvt_f32_bf16(const float* __restrict__ src,
                             unsigned short* __restrict__ dst, int n4) {
  int i = blockIdx.x * blockDim.x + threadIdx.x;
  if (i >= n4) return;
  float4 v = reinterpret_cast<const float4*>(src)[i];
  ushort4v o;
  o.x = f2bf(v.x); o.y = f2bf(v.y); o.z = f2bf(v.z); o.w = f2bf(v.w);
  reinterpret_cast<ushort4v*>(dst)[i] = o;
}

// C = A[M][1024] @ Bw[N][1024]^T  (NT GEMM, bf16 in, fp32 acc)
// MODE 0: QKV with fused RoPE epilogue.  MODE 1: plain fp32 store.
template <int MODE>
__global__ __launch_bounds__(256) void gemm_bt(
    const unsigned short* __restrict__ A, const unsigned short* __restrict__ Bw,
    const float* __restrict__ cosT, const float* __restrict__ sinT,
    unsigned short* __restrict__ Qh, unsigned short* __restrict__ Kh,
    unsigned short* __restrict__ Vt, float* __restrict__ outF) {
  __shared__ __align__(16) unsigned char smA[2][8192];
  __shared__ __align__(16) unsigned char smB[2][8192];
  const int t = threadIdx.x;
  const int lane = t & 63, wvi = t >> 6;
  const int wr = wvi >> 1, wc = wvi & 1;
  const int g = lane >> 4, li = lane & 15;
  const int row0 = blockIdx.y * 128, col0 = blockIdx.x * 128;

  // staging: element e = i*256 + t, row = e>>2, chunk = e&3 (16B chunks, 64B rows)
  // XOR swizzle: LDS(r,c) holds global chunk c ^ (r&3)
  const int schunk = (t & 3) ^ ((t >> 2) & 3);
  const size_t arow = (size_t)(row0 + (t >> 2)) * 1024 + schunk * 8;
  const size_t brow = (size_t)(col0 + (t >> 2)) * 1024 + schunk * 8;

  f32x4 acc[4][4];
#pragma unroll
  for (int mi = 0; mi < 4; ++mi)
#pragma unroll
    for (int ni = 0; ni < 4; ++ni) acc[mi][ni] = (f32x4){0.f, 0.f, 0.f, 0.f};

  auto stage = [&](int buf, int k0) {
    GLDS16(A + arow + k0, &smA[buf][t * 16]);
    GLDS16(A + arow + 64 * 1024 + k0, &smA[buf][4096 + t * 16]);
    GLDS16(Bw + brow + k0, &smB[buf][t * 16]);
    GLDS16(Bw + brow + 64 * 1024 + k0, &smB[buf][4096 + t * 16]);
  };

  stage(0, 0);
  for (int kk = 0; kk < 32; ++kk) {
    __syncthreads();  // drains vmcnt -> buf ready; protects overwrite
    const int buf = kk & 1;
    if (kk < 31) stage(buf ^ 1, (kk + 1) * 32);
    bf16x8 af[4], bfr[4];
#pragma unroll
    for (int mi = 0; mi < 4; ++mi)
      af[mi] = *reinterpret_cast<const bf16x8*>(
          &smA[buf][((wr * 64 + mi * 16 + li) << 6) + ((g ^ (li & 3)) << 4)]);
#pragma unroll
    for (int ni = 0; ni < 4; ++ni)
      bfr[ni] = *reinterpret_cast<const bf16x8*>(
          &smB[buf][((wc * 64 + ni * 16 + li) << 6) + ((g ^ (li & 3)) << 4)]);
#pragma unroll
    for (int mi = 0; mi < 4; ++mi)
#pragma unroll
      for (int ni = 0; ni < 4; ++ni)
        acc[mi][ni] = __builtin_amdgcn_mfma_f32_16x16x32_bf16(
            af[mi], bfr[ni], acc[mi][ni], 0, 0, 0);
  }

  // Epilogue. C-layout: col = lane&15, row = (lane>>4)*4 + reg.
#pragma unroll
  for (int mi = 0; mi < 4; ++mi) {
    const int rowb = row0 + wr * 64 + mi * 16 + g * 4;
#pragma unroll
    for (int ni = 0; ni < 4; ++ni) {
      const int col = col0 + wc * 64 + ni * 16 + li;
#pragma unroll
      for (int r = 0; r < 4; ++r) {
        float v = acc[mi][ni][r];
        const int rr = rowb + r;
        if (MODE == 1) {
          outF[(size_t)rr * 1024 + col] = v;
        } else {
          const int s = rr & 2047, b = rr >> 11;
          const int jj = col & 1023;
          const int h = jj >> 6, d = jj & 63;
          const int bh = b * 16 + h;
          const int typ = col >> 10;  // block-uniform: 0=q 1=k 2=v
          if (typ == 2) {
            Vt[((size_t)bh * 64 + d) * 2048 + s] = f2bf(v);
          } else {
            const float cs = cosT[s * 32 + (d >> 1)];
            const float sn = sinT[s * 32 + (d >> 1)];
            const float pr = __shfl_xor(v, 1);  // partner col d^1
            float rv = (d & 1) ? (pr * sn + v * cs) : (v * cs - pr * sn);
            if (typ == 0) rv *= 0.125f;  // fold softmax scale into Q
            unsigned short* dst = (typ == 0) ? Qh : Kh;
            dst[((size_t)bh * 2048 + s) * 64 + d] = f2bf(rv);
          }
        }
      }
    }
  }
}

// Causal flash attention. Q pre-scaled. Qh,Kh: [bh][s][64]; Vt: [bh][64][s].
// Block: 4 waves, QBLK=64 (16 rows/wave), KVBLK=64.
__global__ __launch_bounds__(256) void attn_fwd(
    const unsigned short* __restrict__ Qh, const unsigned short* __restrict__ Kh,
    const unsigned short* __restrict__ Vt, unsigned short* __restrict__ Ob) {
  __shared__ __align__(16) unsigned char smK[2][8192];
  __shared__ __align__(16) unsigned char smV[2][8192];
  __shared__ __align__(16) unsigned short Plds[4][16][72];  // stride 72 kills wr conflicts

  const int t = threadIdx.x, lane = t & 63, w = t >> 6;
  const int g = lane >> 4, li = lane & 15;
  const int qt = blockIdx.x, bh = blockIdx.y;
  const int q0 = qt * 64;

  bf16x8 qa[2];
  {
    const unsigned short* qrow =
        Qh + ((size_t)bh * 2048 + q0 + w * 16 + li) * 64 + g * 8;
    qa[0] = *reinterpret_cast<const bf16x8*>(qrow);
    qa[1] = *reinterpret_cast<const bf16x8*>(qrow + 32);
  }

  float m_[4], l_[4];
  f32x4 oacc[4];
#pragma unroll
  for (int r = 0; r < 4; ++r) { m_[r] = -1e30f; l_[r] = 0.f; }
#pragma unroll
  for (int dt = 0; dt < 4; ++dt) oacc[dt] = (f32x4){0.f, 0.f, 0.f, 0.f};

  const int ntile = qt + 1;

  // staging: e = i*256 + t; row = e>>3, chunk = e&7 (128B rows, 8 chunks)
  // both-sides XOR swizzle: LDS(r,c) holds global chunk c ^ (r&7)
  auto stage = [&](int buf, int kt) {
    const int kv0 = kt * 64;
#pragma unroll
    for (int i = 0; i < 2; ++i) {
      const int e = i * 256 + t;
      const int row = e >> 3;
      const int sc = (e & 7) ^ (row & 7);
      GLDS16(Kh + ((size_t)bh * 2048 + kv0 + row) * 64 + sc * 8, &smK[buf][e * 16]);
      GLDS16(Vt + ((size_t)bh * 64 + row) * 2048 + kv0 + sc * 8, &smV[buf][e * 16]);
    }
  };

  stage(0, 0);
  for (int kt = 0; kt < ntile; ++kt) {
    __syncthreads();
    const int buf = kt & 1;
    if (kt + 1 < ntile) stage(buf ^ 1, kt + 1);

    // S = Q K^T   (rows=q 16, cols=kv 64)
    f32x4 sacc[4];
#pragma unroll
    for (int ct = 0; ct < 4; ++ct) {
      const int rb = (ct * 16 + li) << 7;
      bf16x8 kb0 = *reinterpret_cast<const bf16x8*>(
          &smK[buf][rb + (((0 * 4 + g) ^ (li & 7)) << 4)]);
      bf16x8 kb1 = *reinterpret_cast<const bf16x8*>(
          &smK[buf][rb + (((1 * 4 + g) ^ (li & 7)) << 4)]);
      f32x4 z = (f32x4){0.f, 0.f, 0.f, 0.f};
      z = __builtin_amdgcn_mfma_f32_16x16x32_bf16(qa[0], kb0, z, 0, 0, 0);
      z = __builtin_amdgcn_mfma_f32_16x16x32_bf16(qa[1], kb1, z, 0, 0, 0);
      sacc[ct] = z;
    }
    if (kt == qt) {  // diagonal tile: mask col > row
#pragma unroll
      for (int ct = 0; ct < 4; ++ct)
#pragma unroll
        for (int r = 0; r < 4; ++r)
          if (ct * 16 + li > w * 16 + g * 4 + r) sacc[ct][r] = -1e30f;
    }
    // online softmax (per-row state replicated across the 16-lane group)
    float mnew[4], alpha[4], psum[4];
#pragma unroll
    for (int r = 0; r < 4; ++r) {
      float tm = fmaxf(fmaxf(sacc[0][r], sacc[1][r]), fmaxf(sacc[2][r], sacc[3][r]));
      tm = fmaxf(tm, __shfl_xor(tm, 1));
      tm = fmaxf(tm, __shfl_xor(tm, 2));
      tm = fmaxf(tm, __shfl_xor(tm, 4));
      tm = fmaxf(tm, __shfl_xor(tm, 8));
      const float mn = fmaxf(m_[r], tm);
      mnew[r] = mn;
      alpha[r] = __expf(m_[r] - mn);
      m_[r] = mn;
      psum[r] = 0.f;
    }
#pragma unroll
    for (int ct = 0; ct < 4; ++ct)
#pragma unroll
      for (int r = 0; r < 4; ++r) {
        const float p = __expf(sacc[ct][r] - mnew[r]);
        psum[r] += p;
        Plds[w][g * 4 + r][ct * 16 + li] = f2bf(p);
      }
#pragma unroll
    for (int r = 0; r < 4; ++r) {
      float ps = psum[r];
      ps += __shfl_xor(ps, 1);
      ps += __shfl_xor(ps, 2);
      ps += __shfl_xor(ps, 4);
      ps += __shfl_xor(ps, 8);
      l_[r] = l_[r] * alpha[r] + ps;
#pragma unroll
      for (int dt = 0; dt < 4; ++dt) oacc[dt][r] *= alpha[r];
    }
    __builtin_amdgcn_wave_barrier();  // order P writes vs reads (wave-local)
    bf16x8 pa0, pa1;
    __builtin_memcpy(&pa0, &Plds[w][li][g * 8], 16);       // alias-safe ds_read_b128
    __builtin_memcpy(&pa1, &Plds[w][li][32 + g * 8], 16);
    // O += P V : B-frag from Vt tile (rows=d, cols=kv)
#pragma unroll
    for (int dt = 0; dt < 4; ++dt) {
      const int rb = (dt * 16 + li) << 7;
      bf16x8 vb0 = *reinterpret_cast<const bf16x8*>(
          &smV[buf][rb + (((0 * 4 + g) ^ (li & 7)) << 4)]);
      bf16x8 vb1 = *reinterpret_cast<const bf16x8*>(
          &smV[buf][rb + (((1 * 4 + g) ^ (li & 7)) << 4)]);
      oacc[dt] = __builtin_amdgcn_mfma_f32_16x16x32_bf16(pa0, vb0, oacc[dt], 0, 0, 0);
      oacc[dt] = __builtin_amdgcn_mfma_f32_16x16x32_bf16(pa1, vb1, oacc[dt], 0, 0, 0);
    }
  }

  const int b = bh >> 4, h = bh & 15;
#pragma unroll
  for (int r = 0; r < 4; ++r) {
    const float inv = 1.0f / l_[r];
    const int row = q0 + w * 16 + g * 4 + r;
#pragma unroll
    for (int dt = 0; dt < 4; ++dt)
      Ob[((size_t)b * 2048 + row) * 1024 + h * 64 + dt * 16 + li] =
          f2bf(oacc[dt][r] * inv);
  }
}

extern "C" void kernel_launch(void* const* d_in, const int* in_sizes, int n_in,
                              void* d_out, int out_size, void* d_ws, size_t ws_size,
                              hipStream_t stream) {
  const float* x = (const float*)d_in[0];
  const float* cosT = (const float*)d_in[1];
  const float* sinT = (const float*)d_in[2];
  const float* wq = (const float*)d_in[3];
  const float* wk = (const float*)d_in[4];
  const float* wv = (const float*)d_in[5];
  const float* wo = (const float*)d_in[6];
  float* out = (float*)d_out;

  char* ws = (char*)d_ws;
  unsigned short* xb    = (unsigned short*)(ws);              //  8 MB [4096][1024]
  unsigned short* wqkvb = (unsigned short*)(ws + 8388608);    //  6 MB [3072][1024]
  unsigned short* wob   = (unsigned short*)(ws + 14680064);   //  2 MB [1024][1024]
  unsigned short* Qh    = (unsigned short*)(ws + 16777216);   //  8 MB [32][2048][64]
  unsigned short* Kh    = (unsigned short*)(ws + 25165824);   //  8 MB [32][2048][64]
  unsigned short* Vt    = (unsigned short*)(ws + 33554432);   //  8 MB [32][64][2048]
  unsigned short* Ob    = (unsigned short*)(ws + 41943040);   //  8 MB [4096][1024]

  cvt_f32_bf16<<<4096, 256, 0, stream>>>(x, xb, 1048576);
  cvt_f32_bf16<<<1024, 256, 0, stream>>>(wq, wqkvb, 262144);
  cvt_f32_bf16<<<1024, 256, 0, stream>>>(wk, wqkvb + 1048576, 262144);
  cvt_f32_bf16<<<1024, 256, 0, stream>>>(wv, wqkvb + 2097152, 262144);
  cvt_f32_bf16<<<1024, 256, 0, stream>>>(wo, wob, 262144);

  gemm_bt<0><<<dim3(24, 32), 256, 0, stream>>>(xb, wqkvb, cosT, sinT, Qh, Kh, Vt,
                                               nullptr);
  attn_fwd<<<dim3(32, 32), 256, 0, stream>>>(Qh, Kh, Vt, Ob);
  gemm_bt<1><<<dim3(8, 32), 256, 0, stream>>>(Ob, wob, nullptr, nullptr, nullptr,
                                              nullptr, nullptr, out);
}